// Round 1
// baseline (97.753 us; speedup 1.0000x reference)
//
#include <hip/hip_runtime.h>

#define MUL 128

__global__ __launch_bounds__(256) void cg_tp_kernel(
    const float* __restrict__ x1,
    const float* __restrict__ x2,
    const float* __restrict__ wts,
    float* __restrict__ out,
    int N)
{
    constexpr float INV_SQRT3 = 0.57735026918962576451f;
    constexpr float INV_SQRT2 = 0.70710678118654752440f;

    int gid = blockIdx.x * blockDim.x + threadIdx.x;
    int total = N * MUL;
    if (gid >= total) return;

    int row = gid >> 7;   // gid / 128
    int u   = gid & 127;  // gid % 128

    const float* x1r  = x1  + (size_t)row * 512;
    const float* x2r  = x2  + (size_t)row * 4;
    const float* wr   = wts + (size_t)row * 640;
    float*       outr = out + (size_t)row * 1408;

    // x1 scalar (0e) channel
    float x10 = x1r[u];
    // x1 vector (1o) channel: 3 contiguous floats at 128 + 3u
    float a0 = x1r[128 + u * 3 + 0];
    float a1 = x1r[128 + u * 3 + 1];
    float a2 = x1r[128 + u * 3 + 2];
    // x2: scalar + vector (broadcast across the 128 channels of the row)
    float s  = x2r[0];
    float b0 = x2r[1];
    float b1 = x2r[2];
    float b2 = x2r[3];
    // 5 per-instruction weights for this channel
    float w0 = wr[0 * MUL + u];
    float w1 = wr[1 * MUL + u];
    float w2 = wr[2 * MUL + u];
    float w3 = wr[3 * MUL + u];
    float w4 = wr[4 * MUL + u];

    // out0: 0e x 0e -> 0e   [0, 128)
    outr[u] = w0 * x10 * s;

    // out1: 0e x 1o -> 1o   [128, 512)
    float w1x = w1 * x10;
    outr[128 + u * 3 + 0] = w1x * b0;
    outr[128 + u * 3 + 1] = w1x * b1;
    outr[128 + u * 3 + 2] = w1x * b2;

    // out2: 1o x 0e -> 1o   [512, 896)
    float w2s = w2 * s;
    outr[512 + u * 3 + 0] = w2s * a0;
    outr[512 + u * 3 + 1] = w2s * a1;
    outr[512 + u * 3 + 2] = w2s * a2;

    // out3: 1o . 1o -> 0e   [896, 1024)
    float dot = a0 * b0 + a1 * b1 + a2 * b2;
    outr[896 + u] = w3 * dot * INV_SQRT3;

    // out4: 1o x 1o -> 1e (cross) [1024, 1408)
    float c0 = a1 * b2 - a2 * b1;
    float c1 = a2 * b0 - a0 * b2;
    float c2 = a0 * b1 - a1 * b0;
    float w4s = w4 * INV_SQRT2;
    outr[1024 + u * 3 + 0] = w4s * c0;
    outr[1024 + u * 3 + 1] = w4s * c1;
    outr[1024 + u * 3 + 2] = w4s * c2;
}

extern "C" void kernel_launch(void* const* d_in, const int* in_sizes, int n_in,
                              void* d_out, int out_size, void* d_ws, size_t ws_size,
                              hipStream_t stream)
{
    const float* x1  = (const float*)d_in[0];
    const float* x2  = (const float*)d_in[1];
    const float* wts = (const float*)d_in[2];
    float* out = (float*)d_out;

    int N = in_sizes[0] / 512;  // x1 is [N, 512]
    int total = N * MUL;
    int block = 256;
    int grid = (total + block - 1) / block;
    cg_tp_kernel<<<grid, block, 0, stream>>>(x1, x2, wts, out, N);
}